// Round 5
// baseline (134.551 us; speedup 1.0000x reference)
//
#include <hip/hip_runtime.h>
#include <hip/hip_bf16.h>
#include <stdint.h>

// ===================================================================
// PriorLayer online BP scan, round 7. s_t = norm(diag(p_t) T s_{t-1}).
// Evidence R1-R6: per-epoch cost pinned 4700-5300 cyc under all body
// changes; pipes <31%; 2 blocks/CU serialize perfectly (R3) => some
// per-CU resource saturated but uncounted. Re-derivation: the shared
// constant of ALL rounds is S_T[n][row] (n-stride 528B) whose b128
// B-reads put 8 lanes on the same 4-bank group EVERY read (64x/epoch,
// on the serial chain). SQ_LDS_BANK_CONFLICT likely undercounts the
// phase serialization of this pattern. Changes:
//  - FRAGMENT-MAJOR state layout SB[kb][lane][j]: read side is the
//    canonical linear pattern (lane*16 + kb*1024) = conflict-free
//    12-cyc b128. Write side scatters: 2x b64/lane (~4-way, 16 instrs
//    -- cheap), mapping from C/D row r=w*32+rt*16+quad*4+v to
//    kb=w, slot ((rt*2+(quad>>1))*16+n)*8+(quad&1)*4+v.
//  - BURN 8 -> 6 (epochs 22): contraction ~0.036/step => truncation
//    ~2e-9 << bf16 state-quantization floor (absmax 2^-5 constant).
//  - Partials quad-reduced via 2 shfl_xor pairs (off the serial
//    chain: consumed next epoch); pZL [16 n][8 w] padded to 10;
//    finalize = ONE b128/lane + 2 shfl pairs (replaces 4 conflicted
//    b128s of R6 / 512 broadcasts of R5).
//  - Keep: gated burns, plain stores, lgkmcnt-only barrier, 2-deep
//    prefetch ring, 4 MFMA chains of depth 4.
// ===================================================================

#define DIM   256
#define SEQ   65536
#define G     16                    // chunks (MFMA columns) per block
#define CLEN  16                    // output steps per chunk
#define NBLK  (SEQ / (G * CLEN))    // 256 blocks -> 1 per CU
#define BURN  6
#define STEPS (BURN + CLEN)         // 22 (even — pairing relies on it)
#define NW    8
#define TPB   (NW * 64)             // 512
#define PGD   10                    // pZL padded slots per n (f32x2)

typedef short bf16x8 __attribute__((ext_vector_type(8)));
typedef float f32x4  __attribute__((ext_vector_type(4)));
typedef float f32x2  __attribute__((ext_vector_type(2)));

static __device__ __forceinline__ unsigned short f2bf(float x) {
  __hip_bfloat16 h = __float2bfloat16(x);
  return *reinterpret_cast<unsigned short*>(&h);
}

// LDS-only barrier: do NOT drain vmcnt (global stores / prefetch loads
// stay in flight). lgkmcnt(0) orders all ds ops.
static __device__ __forceinline__ void lds_barrier() {
  asm volatile("s_waitcnt lgkmcnt(0)" ::: "memory");
  __builtin_amdgcn_s_barrier();
}

__global__ __launch_bounds__(TPB)
void prior_scan_kernel(const float* __restrict__ probs,
                       const float* __restrict__ tp,
                       float* __restrict__ out) {
  // SB: double-buffered state in MFMA-B-FRAGMENT-MAJOR order:
  //     SB[buf][kb][lane=quad*16+n][j] holds u[k=kb*32+quad*8+j][n].
  //     Reads are linear in lane (conflict-free); writes scatter.
  // pZL: double-buffered per-(n,w) partials {sum u, sum u*ln u}.
  __shared__ __attribute__((aligned(16))) short SB[2][8][64][8];
  __shared__ __attribute__((aligned(16))) f32x2 pZL[2][G][PGD];

  const int tid  = threadIdx.x;
  const int w    = tid >> 6;
  const int lane = tid & 63;
  const int n    = lane & 15;       // MFMA col = chunk within block
  const int quad = lane >> 4;
  const int cbase = blockIdx.x * G;
  const int rb0 = w * 32 + quad * 4;        // C/D row base, tile 0
  const int rb1 = w * 32 + 16 + quad * 4;   // row-tile 1

  // state-write slots (shorts, within SB[buf][w]):
  //   rt: row r=w*32+rt*16+quad*4+v -> quad'=rt*2+(quad>>1), j=(quad&1)*4+v
  const int wr0 = (((quad >> 1)) * 16 + n) * 8 + (quad & 1) * 4;
  const int wr1 = ((2 + (quad >> 1)) * 16 + n) * 8 + (quad & 1) * 4;

  // ---- T into A-fragments: A[m=lane&15][k=quad*8+j]; row=w*32+rt*16+m
  bf16x8 A[2][8];
#pragma unroll
  for (int rt = 0; rt < 2; rt++) {
    const int row = w * 32 + rt * 16 + n;
#pragma unroll
    for (int kb = 0; kb < 8; kb++) {
      const float* p = tp + row * DIM + kb * 32 + quad * 8;
      f32x4 f0 = *reinterpret_cast<const f32x4*>(p);
      f32x4 f1 = *reinterpret_cast<const f32x4*>(p + 4);
      bf16x8 a;
#pragma unroll
      for (int j = 0; j < 4; j++) {
        a[j]     = (short)f2bf(f0[j]);
        a[4 + j] = (short)f2bf(f1[j]);
      }
      A[rt][kb] = a;
    }
  }

  // ---- init state buf 0 = uniform 1/256 (bf16-exact; scale-invariant;
  //      layout-independent since all elements equal)
  for (int i = tid; i < 8 * 64 * 8; i += TPB)
    (&SB[0][0][0][0])[i] = (short)0x3B80;

  // ---- observation fragment loader (lane-owned, direct from global)
  auto loadp = [&](int s, int rbase, bool clamp) -> f32x4 {
    int t = (cbase + n) * CLEN - BURN + s;
    if (clamp && t < 0) t = 0;      // value unused when t<0
    return *reinterpret_cast<const f32x4*>(probs + (size_t)t * DIM + rbase);
  };

  // 2-deep register prefetch ring
  f32x4 pf[2][2];
  pf[0][0] = loadp(0, rb0, true); pf[0][1] = loadp(0, rb1, true);
  pf[1][0] = loadp(1, rb0, true); pf[1][1] = loadp(1, rb1, true);

  lds_barrier();

  float qp[2][4];                   // q of previous epoch (deferred norm)

  // --- recurrence core: q = (T @ u) .* p  (4 chains of depth 4)
  //     B-reads: LINEAR lane*16B + kb*1024B (conflict-free)
  auto matvec = [&](int cur, float (&q)[2][4]) {
    const short* src = &SB[cur][0][lane][0];
    f32x4 aE0 = {0.f,0.f,0.f,0.f}, aO0 = {0.f,0.f,0.f,0.f};
    f32x4 aE1 = {0.f,0.f,0.f,0.f}, aO1 = {0.f,0.f,0.f,0.f};
#pragma unroll
    for (int kb = 0; kb < 8; kb += 2) {
      bf16x8 b0 = *reinterpret_cast<const bf16x8*>(src + kb * 512);
      bf16x8 b1 = *reinterpret_cast<const bf16x8*>(src + (kb + 1) * 512);
      aE0 = __builtin_amdgcn_mfma_f32_16x16x32_bf16(A[0][kb],     b0, aE0, 0, 0, 0);
      aE1 = __builtin_amdgcn_mfma_f32_16x16x32_bf16(A[1][kb],     b0, aE1, 0, 0, 0);
      aO0 = __builtin_amdgcn_mfma_f32_16x16x32_bf16(A[0][kb + 1], b1, aO0, 0, 0, 0);
      aO1 = __builtin_amdgcn_mfma_f32_16x16x32_bf16(A[1][kb + 1], b1, aO1, 0, 0, 0);
    }
    f32x4 p0 = pf[cur][0], p1 = pf[cur][1];
#pragma unroll
    for (int v = 0; v < 4; v++) {
      q[0][v] = (aE0[v] + aO0[v]) * p0[v];  // C/D: row=quad*4+v, col=n
      q[1][v] = (aE1[v] + aO1[v]) * p1[v];
    }
  };

  auto write_state = [&](int nxt, const float (&q)[2][4]) {
    short* dst = &SB[nxt][w][0][0];
    ushort4 s0, s1;
    s0.x = f2bf(q[0][0] * 0.015625f); s0.y = f2bf(q[0][1] * 0.015625f);
    s0.z = f2bf(q[0][2] * 0.015625f); s0.w = f2bf(q[0][3] * 0.015625f);
    s1.x = f2bf(q[1][0] * 0.015625f); s1.y = f2bf(q[1][1] * 0.015625f);
    s1.z = f2bf(q[1][2] * 0.015625f); s1.w = f2bf(q[1][3] * 0.015625f);
    *reinterpret_cast<ushort4*>(dst + wr0) = s0;
    *reinterpret_cast<ushort4*>(dst + wr1) = s1;
  };

  // --- deferred finalize of epoch e1 (partials in pZL[pbuf])
  auto finalize = [&](int pbuf, int e1) {
    f32x4 r = *reinterpret_cast<const f32x4*>(&pZL[pbuf][n][quad * 2]);
    float Z = r[0] + r[2];          // groups g=2*quad, 2*quad+1
    float L = r[1] + r[3];
    Z += __shfl_xor(Z, 16); Z += __shfl_xor(Z, 32);
    L += __shfl_xor(L, 16); L += __shfl_xor(L, 32);
    const float zi = __builtin_amdgcn_rcpf(Z);
    const int t1 = (cbase + n) * CLEN + (e1 - BURN);
    f32x4 o0, o1;
#pragma unroll
    for (int v = 0; v < 4; v++) { o0[v] = qp[0][v] * zi; o1[v] = qp[1][v] * zi; }
    *reinterpret_cast<f32x4*>(out + (size_t)t1 * DIM + rb0) = o0;
    *reinterpret_cast<f32x4*>(out + (size_t)t1 * DIM + rb1) = o1;
    if (tid < 16)                   // n == tid for these lanes
      out[(size_t)SEQ * DIM + t1] = __logf(Z) - L * zi;
  };

  // --- burn epoch: NO partials, NO finalize, NO qp carry
  auto burn_body = [&](int e, int cur, int nxt) {
    float q[2][4];
    matvec(cur, q);
    pf[cur][0] = loadp(e + 2, rb0, true);   // e+2 <= BURN+1 < STEPS
    pf[cur][1] = loadp(e + 2, rb1, true);
    const int t = (cbase + n) * CLEN - BURN + e;
    if (t < 0) {                    // pre-start: hold uniform state
      ushort4 sp;
      sp.x = sp.y = sp.z = sp.w = (unsigned short)0x3B80;
      short* dst = &SB[nxt][w][0][0];
      *reinterpret_cast<ushort4*>(dst + wr0) = sp;
      *reinterpret_cast<ushort4*>(dst + wr1) = sp;
    } else {
      write_state(nxt, q);
    }
    lds_barrier();
  };

  // --- output epoch: partials (quad-reduced, off-chain) + deferred
  //     finalize of e-1
  auto main_body = [&](int e, int cur, int nxt) {
    float q[2][4];
    matvec(cur, q);
    int ps = e + 2; if (ps > STEPS - 1) ps = STEPS - 1;  // t>=2 for mains
    pf[cur][0] = loadp(ps, rb0, false);     // issue early (vmem slack)
    pf[cur][1] = loadp(ps, rb1, false);
    write_state(nxt, q);

    float sz = 0.f, sl = 0.f;
#pragma unroll
    for (int rt = 0; rt < 2; rt++)
#pragma unroll
      for (int v = 0; v < 4; v++) {
        float qq = q[rt][v];
        sz += qq;
        sl += qq * __logf(qq + 1e-30f);
      }
    // reduce over quad (consumed NEXT epoch -> off the serial chain)
    sz += __shfl_xor(sz, 16); sz += __shfl_xor(sz, 32);
    sl += __shfl_xor(sl, 16); sl += __shfl_xor(sl, 32);
    if (lane < 16) pZL[cur][lane][w] = f32x2{sz, sl};   // n == lane

    if (e > BURN) finalize(nxt, e - 1);     // nxt == (e-1)&1

#pragma unroll
    for (int rt = 0; rt < 2; rt++)
#pragma unroll
      for (int v = 0; v < 4; v++) qp[rt][v] = q[rt][v];
    lds_barrier();
  };

  for (int e = 0; e < BURN; e += 2) {        // BURN even
    burn_body(e, 0, 1);
    burn_body(e + 1, 1, 0);
  }
  for (int e = BURN; e < STEPS; e += 2) {    // STEPS even, BURN even
    main_body(e, 0, 1);
    main_body(e + 1, 1, 0);
  }

  // --- tail: finalize epoch STEPS-1 (partials in pZL[(STEPS-1)&1])
  finalize((STEPS - 1) & 1, STEPS - 1);
}

extern "C" void kernel_launch(void* const* d_in, const int* in_sizes, int n_in,
                              void* d_out, int out_size, void* d_ws, size_t ws_size,
                              hipStream_t stream) {
  const float* probs = (const float*)d_in[0];   // (65536, 256)
  const float* tp    = (const float*)d_in[1];   // (256, 256)
  float* out         = (float*)d_out;           // 65536*256 probs + 65536 H

  hipLaunchKernelGGL(prior_scan_kernel, dim3(NBLK), dim3(TPB), 0, stream,
                     probs, tp, out);
}